// Round 3
// baseline (116.269 us; speedup 1.0000x reference)
//
#include <hip/hip_runtime.h>

#define NQ 6
#define DIM 64
#define NL 8

#define KP  136   // Bs row pitch (bf16 elems); 272 B rows: 16B-aligned b128 reads
#define ROWS 128  // samples per block

typedef __attribute__((ext_vector_type(8))) short short8v;   // 8 bf16 = 4 VGPRs
typedef __attribute__((ext_vector_type(4))) float floatx4;

__device__ inline short f2bf_rne(float f) {
    unsigned u = __float_as_uint(f);
    u += 0x7FFF + ((u >> 16) & 1);           // round-to-nearest-even
    return (short)(u >> 16);
}

// ---------------------------------------------------------------------------
// Prep (verified rounds 1-2): build circuit unitary U, emit to ws:
//   Bs[128][KP] bf16 : rows n<64 = Wr[n][*], n>=64 = Wi[n-64][*];
//                      cols k<64 = bf16_hi(W[n][k]), 64<=k<128 = bf16_lo(W[n][k])
//   M[64][4] fp32 at byte offset 128*KP*2
// ---------------------------------------------------------------------------
__global__ __launch_bounds__(64) void qnn_prep(
    const float* __restrict__ wts,   // [8*6*3] (phi, theta, omega)
    const float* __restrict__ fc_w,  // [4*6]
    void* __restrict__ ws)
{
    __shared__ float gc[48][4];
    const int n   = threadIdx.x;     // amplitude row 0..63
    const int col = blockIdx.x;      // basis column 0..63

    if (n < 48) {
        float phi = wts[n*3+0], th = wts[n*3+1], om = wts[n*3+2];
        float ch = cosf(0.5f*th), sh = sinf(0.5f*th);
        float p  = 0.5f*(phi+om), m  = 0.5f*(phi-om);
        gc[n][0] = cosf(p)*ch;
        gc[n][1] = sinf(p)*ch;
        gc[n][2] = cosf(m)*sh;
        gc[n][3] = sinf(m)*sh;
    }
    __syncthreads();

    float ar = (n == col) ? 1.0f : 0.0f;
    float ai = 0.0f;

    #pragma unroll
    for (int l = 0; l < NL; ++l) {
        #pragma unroll
        for (int q = 0; q < NQ; ++q) {
            const int g     = l*NQ + q;
            const int shift = 5 - q;
            const int mask  = 1 << shift;
            const int b     = (n >> shift) & 1;
            const float cpch = gc[g][0];
            const float spch = gc[g][1];
            const float cmsh = gc[g][2];
            const float smsh = gc[g][3];
            const float pr = __shfl_xor(ar, mask, 64);
            const float pi = __shfl_xor(ai, mask, 64);
            const float udr = cpch;
            const float udi = b ?  spch : -spch;
            const float uor = b ?  cmsh : -cmsh;
            const float uoi = -smsh;
            const float nr = udr*ar - udi*ai + uor*pr - uoi*pi;
            const float ni = udr*ai + udi*ar + uor*pi + uoi*pr;
            ar = nr; ai = ni;
        }
        const int r = (l % (NQ - 1)) + 1;
        #pragma unroll
        for (int q = 0; q < NQ; ++q) {
            const int t     = (q + r) % NQ;
            const int cmask = 1 << (5 - q);
            const int tmask = 1 << (5 - t);
            const float pr = __shfl_xor(ar, tmask, 64);
            const float pi = __shfl_xor(ai, tmask, 64);
            const bool ctrl = (n & cmask) != 0;
            ar = ctrl ? pr : ar;
            ai = ctrl ? pi : ai;
        }
    }

    unsigned short* Bs = (unsigned short*)ws;
    unsigned short hr = (unsigned short)f2bf_rne(ar);
    float hrf = __uint_as_float((unsigned)hr << 16);
    unsigned short lr = (unsigned short)f2bf_rne(ar - hrf);
    unsigned short hi = (unsigned short)f2bf_rne(ai);
    float hif = __uint_as_float((unsigned)hi << 16);
    unsigned short li = (unsigned short)f2bf_rne(ai - hif);
    Bs[n*KP + col]           = hr;
    Bs[n*KP + 64 + col]      = lr;
    Bs[(64+n)*KP + col]      = hi;
    Bs[(64+n)*KP + 64 + col] = li;

    if (col == 0) {
        float m0=0.f, m1=0.f, m2=0.f, m3=0.f;
        #pragma unroll
        for (int q = 0; q < NQ; ++q) {
            const float sgn = 1.0f - 2.0f*(float)((n >> (5-q)) & 1);
            m0 = fmaf(sgn, fc_w[0*NQ+q], m0);
            m1 = fmaf(sgn, fc_w[1*NQ+q], m1);
            m2 = fmaf(sgn, fc_w[2*NQ+q], m2);
            m3 = fmaf(sgn, fc_w[3*NQ+q], m3);
        }
        float* Mo = (float*)((char*)ws + 128*KP*2);
        Mo[n*4+0]=m0; Mo[n*4+1]=m1; Mo[n*4+2]=m2; Mo[n*4+3]=m3;
    }
}

// ---------------------------------------------------------------------------
// Main: 128 samples/block, 4 waves, wave owns 32 rows (mt=0,1).
//  - B (W hi|lo, bf16) staged once per block into LDS (only LDS user).
//  - A loaded straight from global into registers in MFMA A-layout
//    ([m=lane&15][k=quad*8+j]) and converted to bf16 in-register.
//  - 4 K-steps x 8 N-tiles of mfma_f32_16x16x32_bf16 (re|im cols).
//  - Epilogue entirely in registers + shfl_xor butterfly over the 16
//    l15-lanes: out[s][c] = (sum_col p*M[col][c]) / (sum_col p) + b[c].
// ---------------------------------------------------------------------------
__global__ __launch_bounds__(256, 2) void qnn_main(
    const float* __restrict__ x,
    const float* __restrict__ fc_b,
    const void* __restrict__ wsv,
    float* __restrict__ out)
{
    __shared__ __align__(16) unsigned short Bs[128*KP];   // 34816 B
    __shared__ float Ml[DIM*4];                           // 1024 B

    const int tid = threadIdx.x;
    const int s0  = blockIdx.x * ROWS;
    const int lane = tid & 63;
    const int w    = tid >> 6;
    const int l15  = lane & 15;
    const int quad = lane >> 4;

    // --- stage B + M into LDS ---
    {
        const floatx4* bg = (const floatx4*)wsv;
        floatx4* bl = (floatx4*)Bs;
        #pragma unroll
        for (int i = 0; i < 9; ++i) {
            int idx = tid + i*256;
            if (idx < 128*KP*2/16) bl[idx] = bg[idx];
        }
        const float* Mg = (const float*)((const char*)wsv + 128*KP*2);
        Ml[tid] = Mg[tid];
    }

    // --- A fragments straight from global into registers (bf16 hi of x) ---
    // frag a[mt][h]: row = s0 + w*32 + mt*16 + l15, cols h*32 + quad*8 .. +7
    short8v afr[2][2];
    #pragma unroll
    for (int mt = 0; mt < 2; ++mt) {
        const size_t row = (size_t)(s0 + w*32 + mt*16 + l15);
        const float* xp = x + row*DIM + quad*8;
        #pragma unroll
        for (int h = 0; h < 2; ++h) {
            float4 u0 = *(const float4*)(xp + h*32);
            float4 u1 = *(const float4*)(xp + h*32 + 4);
            short8v a;
            a[0]=f2bf_rne(u0.x); a[1]=f2bf_rne(u0.y);
            a[2]=f2bf_rne(u0.z); a[3]=f2bf_rne(u0.w);
            a[4]=f2bf_rne(u1.x); a[5]=f2bf_rne(u1.y);
            a[6]=f2bf_rne(u1.z); a[7]=f2bf_rne(u1.w);
            afr[mt][h] = a;
        }
    }
    __syncthreads();   // Bs/Ml ready

    floatx4 acc[2][8];
    #pragma unroll
    for (int mt = 0; mt < 2; ++mt)
        #pragma unroll
        for (int nt = 0; nt < 8; ++nt)
            acc[mt][nt] = (floatx4){0.f, 0.f, 0.f, 0.f};

    #pragma unroll
    for (int kk = 0; kk < 4; ++kk) {
        const int h  = kk & 1;                 // A half (xh reused for W-lo K)
        const int bk = (kk << 5) + quad*8;     // B k-offset (Wh then Wl)
        #pragma unroll
        for (int nt = 0; nt < 8; ++nt) {
            short8v b = *(const short8v*)&Bs[(nt*16 + l15)*KP + bk];
            acc[0][nt] = __builtin_amdgcn_mfma_f32_16x16x32_bf16(afr[0][h], b, acc[0][nt], 0, 0, 0);
            acc[1][nt] = __builtin_amdgcn_mfma_f32_16x16x32_bf16(afr[1][h], b, acc[1][nt], 0, 0, 0);
        }
    }

    // --- epilogue in registers ---
    // Mv[nt][c] = M[nt*16+l15][c]
    floatx4 Mv[4];
    #pragma unroll
    for (int nt = 0; nt < 4; ++nt)
        Mv[nt] = *(const floatx4*)&Ml[(nt*16 + l15)*4];

    float q[2][4][5];
    #pragma unroll
    for (int mt = 0; mt < 2; ++mt)
        #pragma unroll
        for (int r = 0; r < 4; ++r)
            #pragma unroll
            for (int c = 0; c < 5; ++c) q[mt][r][c] = 0.f;

    #pragma unroll
    for (int mt = 0; mt < 2; ++mt)
        #pragma unroll
        for (int nt = 0; nt < 4; ++nt)
            #pragma unroll
            for (int r = 0; r < 4; ++r) {
                const float re = acc[mt][nt][r];
                const float im = acc[mt][nt + 4][r];
                const float p  = fmaf(re, re, im*im);
                q[mt][r][0] = fmaf(p, Mv[nt][0], q[mt][r][0]);
                q[mt][r][1] = fmaf(p, Mv[nt][1], q[mt][r][1]);
                q[mt][r][2] = fmaf(p, Mv[nt][2], q[mt][r][2]);
                q[mt][r][3] = fmaf(p, Mv[nt][3], q[mt][r][3]);
                q[mt][r][4] += p;
            }

    // butterfly over the 16 l15-lanes (xor 1,2,4,8 stays inside the quad)
    #pragma unroll
    for (int mt = 0; mt < 2; ++mt)
        #pragma unroll
        for (int r = 0; r < 4; ++r)
            #pragma unroll
            for (int c = 0; c < 5; ++c) {
                float v = q[mt][r][c];
                v += __shfl_xor(v, 1, 64);
                v += __shfl_xor(v, 2, 64);
                v += __shfl_xor(v, 4, 64);
                v += __shfl_xor(v, 8, 64);
                q[mt][r][c] = v;
            }

    const float b0 = fc_b[0], b1 = fc_b[1], b2 = fc_b[2], b3 = fc_b[3];
    #pragma unroll
    for (int mt = 0; mt < 2; ++mt)
        #pragma unroll
        for (int r = 0; r < 4; ++r) {
            const float inv = 1.0f / q[mt][r][4];
            float4 o;
            o.x = fmaf(q[mt][r][0], inv, b0);
            o.y = fmaf(q[mt][r][1], inv, b1);
            o.z = fmaf(q[mt][r][2], inv, b2);
            o.w = fmaf(q[mt][r][3], inv, b3);
            if (l15 == mt*4 + r) {
                const int srow = w*32 + mt*16 + quad*4 + r;
                *(float4*)(out + (size_t)(s0 + srow)*4) = o;
            }
        }
}

extern "C" void kernel_launch(void* const* d_in, const int* in_sizes, int n_in,
                              void* d_out, int out_size, void* d_ws, size_t ws_size,
                              hipStream_t stream) {
    const float* x    = (const float*)d_in[0];   // [262144, 64]
    const float* wts  = (const float*)d_in[1];   // [8, 6, 3]
    const float* fc_w = (const float*)d_in[2];   // [4, 6]
    const float* fc_b = (const float*)d_in[3];   // [4]
    float* out = (float*)d_out;                  // [262144, 4]

    const int batch = in_sizes[0] / DIM;         // 262144

    qnn_prep<<<DIM, DIM, 0, stream>>>(wts, fc_w, d_ws);
    qnn_main<<<batch / ROWS, 256, 0, stream>>>(x, fc_b, d_ws, out);
}

// Round 4
// 109.308 us; speedup vs baseline: 1.0637x; 1.0637x over previous
//
#include <hip/hip_runtime.h>

#define NQ 6
#define DIM 64
#define NL 8

#define KP  136   // Bs row pitch (bf16 elems); 272 B rows: 16B-aligned b128 reads
#define ROWS 128  // samples per block

typedef __attribute__((ext_vector_type(8))) short    short8v;   // 8 bf16 = 4 VGPRs
typedef __attribute__((ext_vector_type(4))) float    floatx4;
typedef __attribute__((ext_vector_type(4))) _Float16 half4v;    // 4 f16 = 2 VGPRs

__device__ inline short f2bf_rne(float f) {
    unsigned u = __float_as_uint(f);
    u += 0x7FFF + ((u >> 16) & 1);           // round-to-nearest-even
    return (short)(u >> 16);
}

// ---------------------------------------------------------------------------
// Prep (circuit verified rounds 1-3): build unitary U, emit to ws:
//   Bs[128][KP] bf16 : rows n<64 = Wr[n][*], n>=64 = Wi[n-64][*];
//                      cols k<64 = bf16_hi(W[n][k]), 64<=k<128 = bf16_lo(W[n][k])
//   M5h table (f16) at byte offset 128*KP*2: A-fragment-ready for
//   mfma_f32_16x16x16_f16: entry [c2][lane][j] = M5[c2*16+(lane>>4)*4+j][lane&15]
//   where M5[i][c<4] = sum_q sign(i,q) fc_w[c][q], M5[i][4] = 1, else 0.
// ---------------------------------------------------------------------------
__global__ __launch_bounds__(64) void qnn_prep(
    const float* __restrict__ wts,   // [8*6*3] (phi, theta, omega)
    const float* __restrict__ fc_w,  // [4*6]
    void* __restrict__ ws)
{
    __shared__ float gc[48][4];
    const int n   = threadIdx.x;     // amplitude row 0..63
    const int col = blockIdx.x;      // basis column 0..63

    if (n < 48) {
        float phi = wts[n*3+0], th = wts[n*3+1], om = wts[n*3+2];
        float ch = cosf(0.5f*th), sh = sinf(0.5f*th);
        float p  = 0.5f*(phi+om), m  = 0.5f*(phi-om);
        gc[n][0] = cosf(p)*ch;
        gc[n][1] = sinf(p)*ch;
        gc[n][2] = cosf(m)*sh;
        gc[n][3] = sinf(m)*sh;
    }
    __syncthreads();

    float ar = (n == col) ? 1.0f : 0.0f;
    float ai = 0.0f;

    #pragma unroll
    for (int l = 0; l < NL; ++l) {
        #pragma unroll
        for (int q = 0; q < NQ; ++q) {
            const int g     = l*NQ + q;
            const int shift = 5 - q;
            const int mask  = 1 << shift;
            const int b     = (n >> shift) & 1;
            const float cpch = gc[g][0];
            const float spch = gc[g][1];
            const float cmsh = gc[g][2];
            const float smsh = gc[g][3];
            const float pr = __shfl_xor(ar, mask, 64);
            const float pi = __shfl_xor(ai, mask, 64);
            const float udr = cpch;
            const float udi = b ?  spch : -spch;
            const float uor = b ?  cmsh : -cmsh;
            const float uoi = -smsh;
            const float nr = udr*ar - udi*ai + uor*pr - uoi*pi;
            const float ni = udr*ai + udi*ar + uor*pi + uoi*pr;
            ar = nr; ai = ni;
        }
        const int r = (l % (NQ - 1)) + 1;
        #pragma unroll
        for (int q = 0; q < NQ; ++q) {
            const int t     = (q + r) % NQ;
            const int cmask = 1 << (5 - q);
            const int tmask = 1 << (5 - t);
            const float pr = __shfl_xor(ar, tmask, 64);
            const float pi = __shfl_xor(ai, tmask, 64);
            const bool ctrl = (n & cmask) != 0;
            ar = ctrl ? pr : ar;
            ai = ctrl ? pi : ai;
        }
    }

    unsigned short* Bs = (unsigned short*)ws;
    unsigned short hr = (unsigned short)f2bf_rne(ar);
    float hrf = __uint_as_float((unsigned)hr << 16);
    unsigned short lr = (unsigned short)f2bf_rne(ar - hrf);
    unsigned short hi = (unsigned short)f2bf_rne(ai);
    float hif = __uint_as_float((unsigned)hi << 16);
    unsigned short li = (unsigned short)f2bf_rne(ai - hif);
    Bs[n*KP + col]           = hr;
    Bs[n*KP + 64 + col]      = lr;
    Bs[(64+n)*KP + col]      = hi;
    Bs[(64+n)*KP + 64 + col] = li;

    if (col == 0) {
        // M5h A-fragment table: thread n == lane n
        const int cp = n & 15;            // c' = l15
        const int qd = n >> 4;            // quad
        half4v* Mo = (half4v*)((char*)ws + 128*KP*2);
        #pragma unroll
        for (int c2 = 0; c2 < 4; ++c2) {
            half4v h4;
            #pragma unroll
            for (int j = 0; j < 4; ++j) {
                const int i = c2*16 + qd*4 + j;
                float v = 0.f;
                if (cp < 4) {
                    #pragma unroll
                    for (int q = 0; q < NQ; ++q) {
                        const float sgn = 1.0f - 2.0f*(float)((i >> (5-q)) & 1);
                        v = fmaf(sgn, fc_w[cp*NQ + q], v);
                    }
                } else if (cp == 4) {
                    v = 1.0f;             // ones column -> ss
                }
                h4[j] = (_Float16)v;
            }
            Mo[c2*64 + n] = h4;
        }
    }
}

// ---------------------------------------------------------------------------
// Main: 128 samples/block, 4 waves, wave owns 32 samples (st=0,1).
// Main GEMM with A=W (from LDS), B=x (straight from global, bf16-converted
// in-register): acc C-layout = p-precursor [i on (quad,reg), s on l15].
// Epilogue: p = re^2+im^2 -> f16 -> second MFMA chain (16x16x16_f16) against
// the precomputed M5 A-fragment table; one shfl_xor(16) fetches ss; quad-0
// lanes store float4. No LDS epilogue traffic, no butterfly.
// ---------------------------------------------------------------------------
__global__ __launch_bounds__(256, 2) void qnn_main(
    const float* __restrict__ x,
    const float* __restrict__ fc_b,
    const void* __restrict__ wsv,
    float* __restrict__ out)
{
    __shared__ __align__(16) unsigned short Bs[128*KP];   // 34816 B

    const int tid  = threadIdx.x;
    const int s0   = blockIdx.x * ROWS;
    const int lane = tid & 63;
    const int w    = tid >> 6;
    const int l15  = lane & 15;
    const int quad = lane >> 4;

    // --- stage W (bf16 hi|lo) into LDS ---
    {
        const floatx4* bg = (const floatx4*)wsv;
        floatx4* bl = (floatx4*)Bs;
        #pragma unroll
        for (int i = 0; i < 9; ++i) {
            int idx = tid + i*256;
            if (idx < 128*KP*2/16) bl[idx] = bg[idx];
        }
    }

    // --- x fragments (B-operand layout) straight from global ---
    // xf[st][h]: sample row = s0 + w*32 + st*16 + l15, cols h*32 + quad*8 ..+7
    short8v xf[2][2];
    #pragma unroll
    for (int st = 0; st < 2; ++st) {
        const size_t row = (size_t)(s0 + w*32 + st*16 + l15);
        const float* xp = x + row*DIM + quad*8;
        #pragma unroll
        for (int h = 0; h < 2; ++h) {
            float4 u0 = *(const float4*)(xp + h*32);
            float4 u1 = *(const float4*)(xp + h*32 + 4);
            short8v a;
            a[0]=f2bf_rne(u0.x); a[1]=f2bf_rne(u0.y);
            a[2]=f2bf_rne(u0.z); a[3]=f2bf_rne(u0.w);
            a[4]=f2bf_rne(u1.x); a[5]=f2bf_rne(u1.y);
            a[6]=f2bf_rne(u1.z); a[7]=f2bf_rne(u1.w);
            xf[st][h] = a;
        }
    }
    __syncthreads();   // Bs ready

    floatx4 acc[2][8];
    #pragma unroll
    for (int st = 0; st < 2; ++st)
        #pragma unroll
        for (int mt = 0; mt < 8; ++mt)
            acc[st][mt] = (floatx4){0.f, 0.f, 0.f, 0.f};

    #pragma unroll
    for (int kk = 0; kk < 4; ++kk) {
        const int h  = kk & 1;                 // x-hi reused for W-lo K range
        const int bk = (kk << 5) + quad*8;
        short8v wf[8];
        #pragma unroll
        for (int mt = 0; mt < 8; ++mt)
            wf[mt] = *(const short8v*)&Bs[(mt*16 + l15)*KP + bk];
        #pragma unroll
        for (int mt = 0; mt < 8; ++mt) {
            acc[0][mt] = __builtin_amdgcn_mfma_f32_16x16x32_bf16(wf[mt], xf[0][h], acc[0][mt], 0, 0, 0);
            acc[1][mt] = __builtin_amdgcn_mfma_f32_16x16x32_bf16(wf[mt], xf[1][h], acc[1][mt], 0, 0, 0);
        }
    }

    // --- epilogue: out[c][s] = sum_i M5[i][c] * p[i][s] via f16 MFMA ---
    const half4v* Mg = (const half4v*)((const char*)wsv + 128*KP*2);
    half4v a2[4];
    #pragma unroll
    for (int c2 = 0; c2 < 4; ++c2) a2[c2] = Mg[c2*64 + lane];

    const float b0 = fc_b[0], b1 = fc_b[1], b2 = fc_b[2], b3 = fc_b[3];

    #pragma unroll
    for (int st = 0; st < 2; ++st) {
        floatx4 d2 = (floatx4){0.f, 0.f, 0.f, 0.f};
        #pragma unroll
        for (int c2 = 0; c2 < 4; ++c2) {
            half4v pb;
            #pragma unroll
            for (int r = 0; r < 4; ++r) {
                const float re = acc[st][c2][r];
                const float im = acc[st][c2 + 4][r];
                pb[r] = (_Float16)fmaf(re, re, im*im);
            }
            d2 = __builtin_amdgcn_mfma_f32_16x16x16f16(a2[c2], pb, d2, 0, 0, 0);
        }
        // d2 reg r = D2[row=quad*4+r][col=l15]; rows 0..3 = logits c, row 4 = ss
        const float ssv = __shfl_xor(d2[0], 16, 64);  // quad0 <- quad1 row4
        if (quad == 0) {
            const float inv = 1.0f / ssv;
            float4 o;
            o.x = fmaf(d2[0], inv, b0);
            o.y = fmaf(d2[1], inv, b1);
            o.z = fmaf(d2[2], inv, b2);
            o.w = fmaf(d2[3], inv, b3);
            *(float4*)(out + (size_t)(s0 + w*32 + st*16 + l15)*4) = o;
        }
    }
}

extern "C" void kernel_launch(void* const* d_in, const int* in_sizes, int n_in,
                              void* d_out, int out_size, void* d_ws, size_t ws_size,
                              hipStream_t stream) {
    const float* x    = (const float*)d_in[0];   // [262144, 64]
    const float* wts  = (const float*)d_in[1];   // [8, 6, 3]
    const float* fc_w = (const float*)d_in[2];   // [4, 6]
    const float* fc_b = (const float*)d_in[3];   // [4]
    float* out = (float*)d_out;                  // [262144, 4]

    const int batch = in_sizes[0] / DIM;         // 262144

    qnn_prep<<<DIM, DIM, 0, stream>>>(wts, fc_w, d_ws);
    qnn_main<<<batch / ROWS, 256, 0, stream>>>(x, fc_b, d_ws, out);
}

// Round 5
// 107.185 us; speedup vs baseline: 1.0848x; 1.0198x over previous
//
#include <hip/hip_runtime.h>

#define NQ 6
#define DIM 64
#define NL 8

#define KP   136  // Bs row pitch (bf16 elems); 272 B rows: 16B-aligned b128 reads
#define ROWS 128  // samples per tile
#define TPB  4    // tiles per block (grid = batch / (ROWS*TPB) = 512 blocks)

typedef __attribute__((ext_vector_type(8))) short    short8v;   // 8 bf16 = 4 VGPRs
typedef __attribute__((ext_vector_type(4))) float    floatx4;
typedef __attribute__((ext_vector_type(4))) _Float16 half4v;    // 4 f16 = 2 VGPRs

__device__ inline short f2bf_rne(float f) {
    unsigned u = __float_as_uint(f);
    u += 0x7FFF + ((u >> 16) & 1);           // round-to-nearest-even
    return (short)(u >> 16);
}

// ---------------------------------------------------------------------------
// Prep (circuit verified rounds 1-4): build unitary U, emit to ws:
//   Bs[128][KP] bf16 : rows n<64 = Wr[n][*], n>=64 = Wi[n-64][*];
//                      cols k<64 = bf16_hi(W[n][k]), 64<=k<128 = bf16_lo(W[n][k])
//   M5h table (f16) at byte offset 128*KP*2: A-fragment-ready for
//   mfma_f32_16x16x16_f16: entry [c2][lane][j] = M5[c2*16+(lane>>4)*4+j][lane&15]
//   where M5[i][c<4] = sum_q sign(i,q) fc_w[c][q], M5[i][4] = 1, else 0.
// ---------------------------------------------------------------------------
__global__ __launch_bounds__(64) void qnn_prep(
    const float* __restrict__ wts,   // [8*6*3] (phi, theta, omega)
    const float* __restrict__ fc_w,  // [4*6]
    void* __restrict__ ws)
{
    __shared__ float gc[48][4];
    const int n   = threadIdx.x;     // amplitude row 0..63
    const int col = blockIdx.x;      // basis column 0..63

    if (n < 48) {
        float phi = wts[n*3+0], th = wts[n*3+1], om = wts[n*3+2];
        float ch = cosf(0.5f*th), sh = sinf(0.5f*th);
        float p  = 0.5f*(phi+om), m  = 0.5f*(phi-om);
        gc[n][0] = cosf(p)*ch;
        gc[n][1] = sinf(p)*ch;
        gc[n][2] = cosf(m)*sh;
        gc[n][3] = sinf(m)*sh;
    }
    __syncthreads();

    float ar = (n == col) ? 1.0f : 0.0f;
    float ai = 0.0f;

    #pragma unroll
    for (int l = 0; l < NL; ++l) {
        #pragma unroll
        for (int q = 0; q < NQ; ++q) {
            const int g     = l*NQ + q;
            const int shift = 5 - q;
            const int mask  = 1 << shift;
            const int b     = (n >> shift) & 1;
            const float cpch = gc[g][0];
            const float spch = gc[g][1];
            const float cmsh = gc[g][2];
            const float smsh = gc[g][3];
            const float pr = __shfl_xor(ar, mask, 64);
            const float pi = __shfl_xor(ai, mask, 64);
            const float udr = cpch;
            const float udi = b ?  spch : -spch;
            const float uor = b ?  cmsh : -cmsh;
            const float uoi = -smsh;
            const float nr = udr*ar - udi*ai + uor*pr - uoi*pi;
            const float ni = udr*ai + udi*ar + uor*pi + uoi*pr;
            ar = nr; ai = ni;
        }
        const int r = (l % (NQ - 1)) + 1;
        #pragma unroll
        for (int q = 0; q < NQ; ++q) {
            const int t     = (q + r) % NQ;
            const int cmask = 1 << (5 - q);
            const int tmask = 1 << (5 - t);
            const float pr = __shfl_xor(ar, tmask, 64);
            const float pi = __shfl_xor(ai, tmask, 64);
            const bool ctrl = (n & cmask) != 0;
            ar = ctrl ? pr : ar;
            ai = ctrl ? pi : ai;
        }
    }

    unsigned short* Bs = (unsigned short*)ws;
    unsigned short hr = (unsigned short)f2bf_rne(ar);
    float hrf = __uint_as_float((unsigned)hr << 16);
    unsigned short lr = (unsigned short)f2bf_rne(ar - hrf);
    unsigned short hi = (unsigned short)f2bf_rne(ai);
    float hif = __uint_as_float((unsigned)hi << 16);
    unsigned short li = (unsigned short)f2bf_rne(ai - hif);
    Bs[n*KP + col]           = hr;
    Bs[n*KP + 64 + col]      = lr;
    Bs[(64+n)*KP + col]      = hi;
    Bs[(64+n)*KP + 64 + col] = li;

    if (col == 0) {
        const int cp = n & 15;            // c' = l15
        const int qd = n >> 4;            // quad
        half4v* Mo = (half4v*)((char*)ws + 128*KP*2);
        #pragma unroll
        for (int c2 = 0; c2 < 4; ++c2) {
            half4v h4;
            #pragma unroll
            for (int j = 0; j < 4; ++j) {
                const int i = c2*16 + qd*4 + j;
                float v = 0.f;
                if (cp < 4) {
                    #pragma unroll
                    for (int q = 0; q < NQ; ++q) {
                        const float sgn = 1.0f - 2.0f*(float)((i >> (5-q)) & 1);
                        v = fmaf(sgn, fc_w[cp*NQ + q], v);
                    }
                } else if (cp == 4) {
                    v = 1.0f;             // ones column -> ss
                }
                h4[j] = (_Float16)v;
            }
            Mo[c2*64 + n] = h4;
        }
    }
}

// ---------------------------------------------------------------------------
// Main: persistent blocks. 512 blocks x 256 thr (2 blocks/CU, exactly
// resident). Each block: stage W into LDS ONCE, then loop TPB sample-tiles
// with NO barriers: x for tile t+1 double-buffered in raw float4 registers
// while tile t computes (GEMM A=W from LDS, B=x in-register bf16;
// epilogue = f16 MFMA against precomputed M5 fragments; shfl_xor(16) for ss).
// ---------------------------------------------------------------------------
__global__ __launch_bounds__(256, 2) void qnn_main(
    const float* __restrict__ x,
    const float* __restrict__ fc_b,
    const void* __restrict__ wsv,
    float* __restrict__ out)
{
    __shared__ __align__(16) unsigned short Bs[128*KP];   // 34816 B

    const int tid  = threadIdx.x;
    const int lane = tid & 63;
    const int w    = tid >> 6;
    const int l15  = lane & 15;
    const int quad = lane >> 4;
    const int nb   = gridDim.x;                 // 512
    const int rbase = w*32 + l15;               // lane's row offset in a tile

    // --- issue tile-0 x loads first (independent of staging) ---
    float4 xr[2][2][2][2];                      // [buf][st][h][pair]
    {
        const float* xt = x + ((size_t)blockIdx.x*ROWS + rbase)*DIM + quad*8;
        #pragma unroll
        for (int st = 0; st < 2; ++st)
            #pragma unroll
            for (int h = 0; h < 2; ++h) {
                xr[0][st][h][0] = *(const float4*)(xt + st*16*DIM + h*32);
                xr[0][st][h][1] = *(const float4*)(xt + st*16*DIM + h*32 + 4);
            }
    }

    // --- stage W (bf16 hi|lo) into LDS, once ---
    {
        const floatx4* bg = (const floatx4*)wsv;
        floatx4* bl = (floatx4*)Bs;
        #pragma unroll
        for (int i = 0; i < 9; ++i) {
            int idx = tid + i*256;
            if (idx < 128*KP*2/16) bl[idx] = bg[idx];
        }
    }

    // --- M5 A-fragments (once) ---
    const half4v* Mg = (const half4v*)((const char*)wsv + 128*KP*2);
    half4v a2[4];
    #pragma unroll
    for (int c2 = 0; c2 < 4; ++c2) a2[c2] = Mg[c2*64 + lane];

    const float b0 = fc_b[0], b1 = fc_b[1], b2 = fc_b[2], b3 = fc_b[3];

    __syncthreads();   // Bs ready; only barrier in the kernel

    #pragma unroll
    for (int t = 0; t < TPB; ++t) {
        const int buf = t & 1;

        // prefetch next tile's x into the other buffer (no wait forced here)
        if (t < TPB - 1) {
            const size_t tile1 = (size_t)(blockIdx.x + (t+1)*nb);
            const float* xt = x + (tile1*ROWS + rbase)*DIM + quad*8;
            #pragma unroll
            for (int st = 0; st < 2; ++st)
                #pragma unroll
                for (int h = 0; h < 2; ++h) {
                    xr[buf^1][st][h][0] = *(const float4*)(xt + st*16*DIM + h*32);
                    xr[buf^1][st][h][1] = *(const float4*)(xt + st*16*DIM + h*32 + 4);
                }
        }

        // convert current tile to bf16 B-fragments
        short8v xf[2][2];
        #pragma unroll
        for (int st = 0; st < 2; ++st)
            #pragma unroll
            for (int h = 0; h < 2; ++h) {
                const float4 u0 = xr[buf][st][h][0];
                const float4 u1 = xr[buf][st][h][1];
                short8v a;
                a[0]=f2bf_rne(u0.x); a[1]=f2bf_rne(u0.y);
                a[2]=f2bf_rne(u0.z); a[3]=f2bf_rne(u0.w);
                a[4]=f2bf_rne(u1.x); a[5]=f2bf_rne(u1.y);
                a[6]=f2bf_rne(u1.z); a[7]=f2bf_rne(u1.w);
                xf[st][h] = a;
            }

        // K-loop: A = W (LDS), B = x (registers)
        floatx4 acc[2][8];
        #pragma unroll
        for (int st = 0; st < 2; ++st)
            #pragma unroll
            for (int mt = 0; mt < 8; ++mt)
                acc[st][mt] = (floatx4){0.f, 0.f, 0.f, 0.f};

        #pragma unroll
        for (int kk = 0; kk < 4; ++kk) {
            const int h  = kk & 1;               // x-hi reused for W-lo K range
            const int bk = (kk << 5) + quad*8;
            #pragma unroll
            for (int mt = 0; mt < 8; ++mt) {
                const short8v wf = *(const short8v*)&Bs[(mt*16 + l15)*KP + bk];
                acc[0][mt] = __builtin_amdgcn_mfma_f32_16x16x32_bf16(wf, xf[0][h], acc[0][mt], 0, 0, 0);
                acc[1][mt] = __builtin_amdgcn_mfma_f32_16x16x32_bf16(wf, xf[1][h], acc[1][mt], 0, 0, 0);
            }
        }

        // epilogue: out[c][s] = sum_i M5[i][c] * p[i][s] via f16 MFMA
        const size_t s0 = (size_t)(blockIdx.x + t*nb) * ROWS;
        #pragma unroll
        for (int st = 0; st < 2; ++st) {
            floatx4 d2 = (floatx4){0.f, 0.f, 0.f, 0.f};
            #pragma unroll
            for (int c2 = 0; c2 < 4; ++c2) {
                half4v pb;
                #pragma unroll
                for (int r = 0; r < 4; ++r) {
                    const float re = acc[st][c2][r];
                    const float im = acc[st][c2 + 4][r];
                    pb[r] = (_Float16)fmaf(re, re, im*im);
                }
                d2 = __builtin_amdgcn_mfma_f32_16x16x16f16(a2[c2], pb, d2, 0, 0, 0);
            }
            // d2 reg r = D2[row=quad*4+r][col=l15]; rows 0..3 = logits, row 4 = ss
            const float ssv = __shfl_xor(d2[0], 16, 64);  // quad0 <- quad1 row4
            if (quad == 0) {
                const float inv = 1.0f / ssv;
                float4 o;
                o.x = fmaf(d2[0], inv, b0);
                o.y = fmaf(d2[1], inv, b1);
                o.z = fmaf(d2[2], inv, b2);
                o.w = fmaf(d2[3], inv, b3);
                *(float4*)(out + (s0 + w*32 + st*16 + l15)*4) = o;
            }
        }
    }
}

extern "C" void kernel_launch(void* const* d_in, const int* in_sizes, int n_in,
                              void* d_out, int out_size, void* d_ws, size_t ws_size,
                              hipStream_t stream) {
    const float* x    = (const float*)d_in[0];   // [262144, 64]
    const float* wts  = (const float*)d_in[1];   // [8, 6, 3]
    const float* fc_w = (const float*)d_in[2];   // [4, 6]
    const float* fc_b = (const float*)d_in[3];   // [4]
    float* out = (float*)d_out;                  // [262144, 4]

    const int batch = in_sizes[0] / DIM;         // 262144

    qnn_prep<<<DIM, DIM, 0, stream>>>(wts, fc_w, d_ws);
    qnn_main<<<batch / (ROWS*TPB), 256, 0, stream>>>(x, fc_b, d_ws, out);
}